// Round 7
// baseline (444.032 us; speedup 1.0000x reference)
//
#include <hip/hip_runtime.h>
#include <math.h>

#define D 64
#define BN_EPS 1e-5f
#define CH 160          // edges per chunk (edge_agg work unit)
#define BSH 7           // bucket shift: 128 nodes per bucket
#define BCAP 8192       // per-bucket LDS capacity (mean ~1600)

using short8 = __attribute__((ext_vector_type(8))) short;
using f32x4  = __attribute__((ext_vector_type(4))) float;

static __device__ __forceinline__ unsigned short f2bf(float f) {
    unsigned int u = __float_as_uint(f);
    unsigned int r = (u + 0x7fffu + ((u >> 16) & 1u)) >> 16;
    return (unsigned short)r;
}
static __device__ __forceinline__ float clamp60(float x) {
    return fminf(fmaxf(x, -60.f), 60.f);
}

// ---------------- weight prep (fragment-linear bf16) + zero bucket counters ----------------
__global__ __launch_bounds__(256) void prep_weights(
    const float* __restrict__ Wk, const float* __restrict__ Wq,
    const float* __restrict__ Wv, const float* __restrict__ Ws,
    unsigned short* __restrict__ Wfrag, int* __restrict__ bcnt, int nbcnt)
{
    int idx = blockIdx.x * 256 + threadIdx.x;      // 32768 total
    if (idx < nbcnt) bcnt[idx] = 0;
    int i    = idx & 7;
    int lane = (idx >> 3) & 63;
    int kb   = (idx >> 9) & 1;
    int nc   = (idx >> 10) & 3;
    int m    = (idx >> 12) & 3;
    int l    = (idx >> 14) & 1;
    int k = kb * 32 + (lane >> 4) * 8 + i;
    int n = nc * 16 + (lane & 15);
    const float* W = (m == 0) ? Wk : (m == 1) ? Wq : (m == 2) ? Wv : Ws;
    Wfrag[idx] = f2bf(W[(size_t)l * 4096 + k * 64 + n]);
}

// ---------------- fused 4-GEMM via MFMA (unchanged from R6) ----------------
template<bool APPLY_BN>
__global__ __launch_bounds__(256) void gemm_fused(
    const float* x,                       // may alias AGG (own rows only)
    const unsigned short* __restrict__ Wfrag,
    const float* __restrict__ bk, const float* __restrict__ bq,
    const float* __restrict__ bv, const float* __restrict__ bs,
    const float* __restrict__ bias, const float* __restrict__ stats,
    float* __restrict__ EK, unsigned int* __restrict__ QV,
    float* AGG, int nrows)
{
    __shared__ unsigned short xt[64 * 64];   // bf16 tile, XOR-swizzled 16B chunks
    const int t = threadIdx.x;
    const int row0 = blockIdx.x * 64;

    #pragma unroll
    for (int it = 0; it < 4; ++it) {
        int fidx = t + it * 256;
        int r = fidx >> 4, c4 = fidx & 15;
        int grow = row0 + r;
        float4 v = make_float4(0.f, 0.f, 0.f, 0.f);
        if (grow < nrows)
            v = *reinterpret_cast<const float4*>(&x[(size_t)grow * D + c4 * 4]);
        if (APPLY_BN) {
            const float4* st4 = reinterpret_cast<const float4*>(stats);
            float4 sc = st4[32 + c4], sh = st4[48 + c4];
            v.x = fmaxf(v.x, 0.f) * sc.x + sh.x;
            v.y = fmaxf(v.y, 0.f) * sc.y + sh.y;
            v.z = fmaxf(v.z, 0.f) * sc.z + sh.z;
            v.w = fmaxf(v.w, 0.f) * sc.w + sh.w;
        }
        ushort4 b;
        b.x = f2bf(v.x); b.y = f2bf(v.y); b.z = f2bf(v.z); b.w = f2bf(v.w);
        int phys = (c4 >> 1) ^ (r & 7);
        *reinterpret_cast<ushort4*>(&xt[r * 64 + phys * 8 + (c4 & 1) * 4]) = b;
    }
    __syncthreads();

    const int w = t >> 6, lane = t & 63;
    const int rbase = w * 16;

    short8 A[2];
    #pragma unroll
    for (int kb = 0; kb < 2; ++kb) {
        int r = rbase + (lane & 15);
        int c16 = (kb * 4 + (lane >> 4)) ^ (r & 7);
        A[kb] = *reinterpret_cast<const short8*>(&xt[r * 64 + c16 * 8]);
    }

    f32x4 acc[4][4];
    #pragma unroll
    for (int m = 0; m < 4; ++m)
        #pragma unroll
        for (int nc = 0; nc < 4; ++nc)
            acc[m][nc] = (f32x4){0.f, 0.f, 0.f, 0.f};

    #pragma unroll
    for (int nc = 0; nc < 4; ++nc) {
        #pragma unroll
        for (int m = 0; m < 4; ++m) {
            #pragma unroll
            for (int kb = 0; kb < 2; ++kb) {
                short8 B = *reinterpret_cast<const short8*>(
                    &Wfrag[((((m * 4 + nc) * 2 + kb) * 64) + lane) * 8]);
                acc[m][nc] = __builtin_amdgcn_mfma_f32_16x16x32_bf16(A[kb], B, acc[m][nc], 0, 0, 0);
            }
        }
    }

    const int crow = rbase + ((lane >> 4) << 2);
    #pragma unroll
    for (int nc = 0; nc < 4; ++nc) {
        int c = nc * 16 + (lane & 15);
        float bkc = bk[c], bqc = bq[c], bvc = bv[c], bsc = bs[c] + bias[c];
        #pragma unroll
        for (int reg = 0; reg < 4; ++reg) {
            int grow = row0 + crow + reg;
            if (grow < nrows) {
                size_t o = (size_t)grow * D + c;
                EK[o] = __expf(-clamp60(acc[0][nc][reg] + bkc));
                float eq = __expf(-clamp60(acc[1][nc][reg] + bqc));
                QV[o] = ((unsigned int)f2bf(acc[2][nc][reg] + bvc) << 16) | (unsigned int)f2bf(eq);
                AGG[o] = acc[3][nc][reg] + bsc;
            }
        }
    }
}

// ---------------- bucket-binned CSR build ----------------
// counters padded to 64B (stride 16 ints) to avoid TCC line serialization
__global__ __launch_bounds__(256) void bucket_hist(const int* __restrict__ dst,
                                                   int* __restrict__ bcnt, int nedges)
{
    int i = blockIdx.x * 256 + threadIdx.x;
    if (i < nedges) atomicAdd(&bcnt[(dst[i] >> BSH) << 4], 1);
}

// one block: exclusive-scan NB bucket counts; init cursors; zero BN stats; offs[n]=nedges
__global__ __launch_bounds__(1024) void bucket_scan(const int* __restrict__ bcnt,
                                                    int* __restrict__ boff,
                                                    int* __restrict__ bcur,
                                                    float* __restrict__ stats,
                                                    int* __restrict__ offs,
                                                    int NB, int n, int nedges)
{
    __shared__ int tmp[1024];
    const int t = threadIdx.x;
    int v = (t < NB) ? bcnt[t << 4] : 0;
    tmp[t] = v;
    __syncthreads();
    for (int off = 1; off < 1024; off <<= 1) {
        int add = (t >= off) ? tmp[t - off] : 0;
        __syncthreads();
        tmp[t] += add;
        __syncthreads();
    }
    if (t < NB) {
        int ex = tmp[t] - v;
        boff[t] = ex;
        bcur[t << 4] = ex;
    }
    if (t < 128) stats[t] = 0.f;
    if (t == 0) offs[n] = nedges;
}

// emit (src<<BSH | dst&mask) at the bucket's moving write-head (L2-merged writes)
__global__ __launch_bounds__(256) void bucket_emit(const int* __restrict__ src,
                                                   const int* __restrict__ dst,
                                                   int* __restrict__ bcur,
                                                   unsigned int* __restrict__ bin, int nedges)
{
    int i = blockIdx.x * 256 + threadIdx.x;
    if (i < nedges) {
        int d = dst[i];
        int pos = atomicAdd(&bcur[(d >> BSH) << 4], 1);
        bin[pos] = ((unsigned int)src[i] << BSH) | (unsigned int)(d & ((1 << BSH) - 1));
    }
}

// one block per bucket: exact CSR within bucket, all in LDS, coalesced global IO
__global__ __launch_bounds__(256) void bucket_csr(const unsigned int* __restrict__ bin,
                                                  const int* __restrict__ boff,
                                                  const int* __restrict__ bcnt,
                                                  int* __restrict__ offs,
                                                  int* __restrict__ csr_src, int n)
{
    __shared__ unsigned int lsrc[BCAP];
    __shared__ int ldeg[128], loff[128], lcur[128];
    const int t = threadIdx.x;
    const int b = blockIdx.x;
    const int base = boff[b];
    const int cnt  = bcnt[b << 4];

    if (t < 128) ldeg[t] = 0;
    __syncthreads();
    for (int j = t; j < cnt; j += 256)
        atomicAdd(&ldeg[bin[base + j] & ((1 << BSH) - 1)], 1);
    __syncthreads();
    if (t < 128) loff[t] = ldeg[t];
    __syncthreads();
    for (int off = 1; off < 128; off <<= 1) {
        int add = (t < 128 && t >= off) ? loff[t - off] : 0;
        __syncthreads();
        if (t < 128) loff[t] += add;
        __syncthreads();
    }
    if (t < 128) {
        int ex = loff[t] - ldeg[t];
        lcur[t] = ex;
        int node = (b << BSH) + t;
        if (node < n) offs[node] = base + ex;
    }
    __syncthreads();
    for (int j = t; j < cnt; j += 256) {
        unsigned int e = bin[base + j];
        int pos = atomicAdd(&lcur[e & ((1 << BSH) - 1)], 1);
        lsrc[pos] = e >> BSH;
    }
    __syncthreads();
    for (int j = t; j < cnt; j += 256)
        csr_src[base + j] = (int)lsrc[j];
}

// chunk -> first node map via binary search over offs
__global__ __launch_bounds__(256) void nstart_bs(const int* __restrict__ offs,
                                                 int* __restrict__ node_start,
                                                 int n, int NC)
{
    int c = blockIdx.x * 256 + threadIdx.x;
    if (c >= NC) return;
    int target = c * CH;
    int a = 0, bnd = n;
    while (a < bnd) {                 // first idx with offs[idx+1] > target
        int mid = (a + bnd) >> 1;
        if (offs[mid + 1] > target) bnd = mid; else a = mid + 1;
    }
    node_start[c] = a;
}

// ---------------- edge-parallel aggregation over CSR chunks ----------------
__global__ __launch_bounds__(256) void edge_agg(
    const int* __restrict__ csr_src, const int* __restrict__ offs,
    const int* __restrict__ node_start,
    const float* __restrict__ EK, const unsigned int* __restrict__ QV,
    float* __restrict__ AGG, int nnodes)
{
    const int lane  = threadIdx.x & 63;
    const int chunk = __builtin_amdgcn_readfirstlane((int)((blockIdx.x * 256 + threadIdx.x) >> 6));
    const int Etot  = offs[nnodes];
    const int e0 = chunk * CH;
    if (e0 >= Etot) return;
    const int e1 = min(e0 + CH, Etot);

    int n      = node_start[chunk];
    int nstart = offs[n];
    int nend   = offs[n + 1];

    float acc = 0.f;
    float ek  = EK[((size_t)n << 6) | lane];

    auto flush = [&](bool partial) {
        int idx = (n << 6) | lane;
        if (partial) atomicAdd(&AGG[idx], acc);
        else         AGG[idx] += acc;
    };
    auto advance = [&](int eidx) {
        do { ++n; } while (offs[n + 1] == eidx);   // skip empty nodes
        nstart = eidx;
        nend   = offs[n + 1];
        acc = 0.f;
        ek  = EK[((size_t)n << 6) | lane];
    };

    for (int e = e0; e < e1; e += 64) {
        const int cnt = min(64, e1 - e);
        int sAll = (lane < cnt) ? csr_src[e + lane] : 0;
        for (int b = 0; b < cnt; b += 16) {
            const int bc = min(16, cnt - b);
            unsigned int p[16];
            #pragma unroll
            for (int u = 0; u < 16; ++u) {
                if (u < bc) {
                    int s = __shfl(sAll, b + u);
                    p[u] = QV[((size_t)s << 6) | lane];
                }
            }
            #pragma unroll
            for (int u = 0; u < 16; ++u) {
                if (u < bc) {
                    int eidx = e + b + u;
                    if (eidx == nend) { flush(nstart < e0); advance(eidx); }
                    float eq = __uint_as_float(p[u] << 16);
                    float vv = __uint_as_float(p[u] & 0xffff0000u);
                    float g  = __builtin_amdgcn_rcpf(fmaf(ek, eq, 1.0f));
                    acc = fmaf(g, vv, acc);
                }
            }
        }
    }
    flush((nstart < e0) || (nend > e1));
}

// ---------------- per-feature BN stats of relu(AGG) (no write-back) ----------------
__global__ __launch_bounds__(256) void relu_stats(
    const float* __restrict__ AGG, float* __restrict__ stats, int n4)
{
    __shared__ float ls[128];
    const int t = threadIdx.x;
    if (t < 128) ls[t] = 0.f;
    __syncthreads();
    int idx = blockIdx.x * 256 + t;
    const int stride = gridDim.x * 256;
    const int f0 = (idx << 2) & 63;
    float s0=0,s1=0,s2=0,s3=0,q0=0,q1=0,q2=0,q3=0;
    for (; idx < n4; idx += stride) {
        float4 a = reinterpret_cast<const float4*>(AGG)[idx];
        a.x = fmaxf(a.x, 0.f); a.y = fmaxf(a.y, 0.f);
        a.z = fmaxf(a.z, 0.f); a.w = fmaxf(a.w, 0.f);
        s0 += a.x; q0 = fmaf(a.x, a.x, q0);
        s1 += a.y; q1 = fmaf(a.y, a.y, q1);
        s2 += a.z; q2 = fmaf(a.z, a.z, q2);
        s3 += a.w; q3 = fmaf(a.w, a.w, q3);
    }
    atomicAdd(&ls[f0],     s0); atomicAdd(&ls[f0 + 1],     s1);
    atomicAdd(&ls[f0 + 2], s2); atomicAdd(&ls[f0 + 3],     s3);
    atomicAdd(&ls[64 + f0],     q0); atomicAdd(&ls[64 + f0 + 1], q1);
    atomicAdd(&ls[64 + f0 + 2], q2); atomicAdd(&ls[64 + f0 + 3], q3);
    __syncthreads();
    if (t < 128) atomicAdd(&stats[t], ls[t]);
}

// ---------------- finalize: scale/shift; re-zero sums for next layer ----------------
__global__ void finalize_stats(float* __restrict__ stats,
                               const float* __restrict__ gamma,
                               const float* __restrict__ beta, int nrows)
{
    int t = threadIdx.x;  // 64 threads
    float invN = 1.0f / (float)nrows;
    float mean = stats[t] * invN;
    float var  = stats[64 + t] * invN - mean * mean;
    float sc   = gamma[t] * rsqrtf(var + BN_EPS);
    stats[128 + t] = sc;
    stats[192 + t] = beta[t] - mean * sc;
    stats[t] = 0.f;
    stats[64 + t] = 0.f;
}

// ---------------- apply (final layer): out = relu(AGG)*scale + shift ----------------
__global__ __launch_bounds__(256) void apply_bn(
    const float* __restrict__ AGG, const float* __restrict__ stats,
    float* __restrict__ xout, int ntot4)
{
    int idx = blockIdx.x * 256 + threadIdx.x;
    const int stride = gridDim.x * 256;
    const float4* st4 = reinterpret_cast<const float4*>(stats);
    for (; idx < ntot4; idx += stride) {
        float4 a = reinterpret_cast<const float4*>(AGG)[idx];
        int c4 = idx & 15;
        float4 sc = st4[32 + c4];
        float4 sh = st4[48 + c4];
        float4 o;
        o.x = fmaxf(a.x, 0.f) * sc.x + sh.x;
        o.y = fmaxf(a.y, 0.f) * sc.y + sh.y;
        o.z = fmaxf(a.z, 0.f) * sc.z + sh.z;
        o.w = fmaxf(a.w, 0.f) * sc.w + sh.w;
        reinterpret_cast<float4*>(xout)[idx] = o;
    }
}

extern "C" void kernel_launch(void* const* d_in, const int* in_sizes, int n_in,
                              void* d_out, int out_size, void* d_ws, size_t ws_size,
                              hipStream_t stream)
{
    const float* x     = (const float*)d_in[0];
    const int*   ei    = (const int*)d_in[1];
    const float* Wk    = (const float*)d_in[3];
    const float* bk    = (const float*)d_in[4];
    const float* Wq    = (const float*)d_in[5];
    const float* bq    = (const float*)d_in[6];
    const float* Wv    = (const float*)d_in[7];
    const float* bv    = (const float*)d_in[8];
    const float* Ws    = (const float*)d_in[9];
    const float* bs    = (const float*)d_in[10];
    const float* bias  = (const float*)d_in[11];
    const float* gamma = (const float*)d_in[12];
    const float* beta  = (const float*)d_in[13];

    const int nrows  = in_sizes[0] / D;     // 100000
    const int nedges = in_sizes[1] / 2;     // 1250000
    const int nm     = nrows * D;
    const int NB     = (nrows + (1 << BSH) - 1) >> BSH;   // 782 buckets
    const int NC     = (nedges + CH - 1) / CH;            // chunks

    float* out = (float*)d_out;
    float* ws  = (float*)d_ws;
    float* EK  = ws;                                     // nm f32
    unsigned int* QV = (unsigned int*)(EK + nm);         // nm u32
    float* AGG = (float*)(QV + nm);                      // nm f32
    float* stats = AGG + nm;                             // 256 f32
    int* offs    = (int*)(stats + 256);                  // nrows+1
    unsigned int* bin = (unsigned int*)(offs + nrows + 1); // nedges
    int* csr_src = (int*)(bin + nedges);                 // nedges
    int* bcnt    = csr_src + nedges;                     // NB*16 (64B-padded)
    int* bcur    = bcnt + NB * 16;                       // NB*16
    int* boff    = bcur + NB * 16;                       // NB
    int* nstart_map = boff + NB;                         // NC
    unsigned short* Wfrag = (unsigned short*)(nstart_map + NC);  // 32768 u16

    const int* srcI = ei;
    const int* dstI = ei + nedges;

    const int gemm_blocks = (nrows + 63) / 64;
    const int edge_blocks = (nedges + 255) / 256;
    const int agg_blocks  = (NC + 3) / 4;                // 1 wave per chunk

    // ---- weight prep (also zeroes bucket counters) + binned CSR build ----
    prep_weights<<<128, 256, 0, stream>>>(Wk, Wq, Wv, Ws, Wfrag, bcnt, NB * 16);
    bucket_hist<<<edge_blocks, 256, 0, stream>>>(dstI, bcnt, nedges);
    bucket_scan<<<1, 1024, 0, stream>>>(bcnt, boff, bcur, stats, offs, NB, nrows, nedges);
    bucket_emit<<<edge_blocks, 256, 0, stream>>>(srcI, dstI, bcur, bin, nedges);
    bucket_csr<<<NB, 256, 0, stream>>>(bin, boff, bcnt, offs, csr_src, nrows);
    nstart_bs<<<(NC + 255) / 256, 256, 0, stream>>>(offs, nstart_map, nrows, NC);

    // ---- layer 1 ----
    gemm_fused<false><<<gemm_blocks, 256, 0, stream>>>(x, Wfrag,
        bk, bq, bv, bs, bias, stats, EK, QV, AGG, nrows);
    edge_agg<<<agg_blocks, 256, 0, stream>>>(csr_src, offs, nstart_map, EK, QV, AGG, nrows);
    relu_stats<<<1024, 256, 0, stream>>>(AGG, stats, nm / 4);
    finalize_stats<<<1, 64, 0, stream>>>(stats, gamma, beta, nrows);

    // ---- layer 2 (relu+BN of layer 1 fused into MFMA staging) ----
    gemm_fused<true><<<gemm_blocks, 256, 0, stream>>>(AGG, Wfrag + 16384,
        bk + D, bq + D, bv + D, bs + D, bias + D, stats, EK, QV, AGG, nrows);
    edge_agg<<<agg_blocks, 256, 0, stream>>>(csr_src, offs, nstart_map, EK, QV, AGG, nrows);
    relu_stats<<<1024, 256, 0, stream>>>(AGG, stats, nm / 4);
    finalize_stats<<<1, 64, 0, stream>>>(stats, gamma + D, beta + D, nrows);
    apply_bn<<<2048, 256, 0, stream>>>(AGG, stats, out, nm / 4);
}

// Round 8
// 418.637 us; speedup vs baseline: 1.0607x; 1.0607x over previous
//
#include <hip/hip_runtime.h>
#include <math.h>

#define D 64
#define BN_EPS 1e-5f
#define CH 160   // edges per chunk (edge_agg work unit)

using short8 = __attribute__((ext_vector_type(8))) short;
using f32x4  = __attribute__((ext_vector_type(4))) float;

static __device__ __forceinline__ unsigned short f2bf(float f) {
    unsigned int u = __float_as_uint(f);
    unsigned int r = (u + 0x7fffu + ((u >> 16) & 1u)) >> 16;
    return (unsigned short)r;
}
static __device__ __forceinline__ float bf2f(unsigned short u) {
    return __uint_as_float(((unsigned int)u) << 16);
}
static __device__ __forceinline__ float clamp60(float x) {
    return fminf(fmaxf(x, -60.f), 60.f);
}

// ---------------- weight prep: fragment-linear bf16 for mfma_f32_16x16x32_bf16 ----------------
__global__ __launch_bounds__(256) void prep_weights(
    const float* __restrict__ Wk, const float* __restrict__ Wq,
    const float* __restrict__ Wv, const float* __restrict__ Ws,
    unsigned short* __restrict__ Wfrag)
{
    int idx = blockIdx.x * 256 + threadIdx.x;      // 32768 total
    int i    = idx & 7;
    int lane = (idx >> 3) & 63;
    int kb   = (idx >> 9) & 1;
    int nc   = (idx >> 10) & 3;
    int m    = (idx >> 12) & 3;
    int l    = (idx >> 14) & 1;
    int k = kb * 32 + (lane >> 4) * 8 + i;
    int n = nc * 16 + (lane & 15);
    const float* W = (m == 0) ? Wk : (m == 1) ? Wq : (m == 2) ? Wv : Ws;
    Wfrag[idx] = f2bf(W[(size_t)l * 4096 + k * 64 + n]);
}

// ---------------- fused 4-GEMM via MFMA ----------------
// EKh = bf16(exp(-clamp(x@Wk+bk))); QV = {bf16(v)<<16 | bf16(exp(-clamp(q)))}; AGG = x@Ws+bs+bias.
// APPLY_BN: input is raw layer-1 AGG; apply relu + BN (stats[128..255]) while staging.
template<bool APPLY_BN>
__global__ __launch_bounds__(256) void gemm_fused(
    const float* x,                       // may alias AGG (own rows only)
    const unsigned short* __restrict__ Wfrag,
    const float* __restrict__ bk, const float* __restrict__ bq,
    const float* __restrict__ bv, const float* __restrict__ bs,
    const float* __restrict__ bias, const float* __restrict__ stats,
    unsigned short* __restrict__ EKh, unsigned int* __restrict__ QV,
    float* AGG, int nrows)
{
    __shared__ unsigned short xt[64 * 64];   // bf16 tile, XOR-swizzled 16B chunks
    const int t = threadIdx.x;
    const int row0 = blockIdx.x * 64;

    #pragma unroll
    for (int it = 0; it < 4; ++it) {
        int fidx = t + it * 256;
        int r = fidx >> 4, c4 = fidx & 15;
        int grow = row0 + r;
        float4 v = make_float4(0.f, 0.f, 0.f, 0.f);
        if (grow < nrows)
            v = *reinterpret_cast<const float4*>(&x[(size_t)grow * D + c4 * 4]);
        if (APPLY_BN) {
            const float4* st4 = reinterpret_cast<const float4*>(stats);
            float4 sc = st4[32 + c4], sh = st4[48 + c4];
            v.x = fmaxf(v.x, 0.f) * sc.x + sh.x;
            v.y = fmaxf(v.y, 0.f) * sc.y + sh.y;
            v.z = fmaxf(v.z, 0.f) * sc.z + sh.z;
            v.w = fmaxf(v.w, 0.f) * sc.w + sh.w;
        }
        ushort4 b;
        b.x = f2bf(v.x); b.y = f2bf(v.y); b.z = f2bf(v.z); b.w = f2bf(v.w);
        int phys = (c4 >> 1) ^ (r & 7);      // 16B-chunk XOR swizzle
        *reinterpret_cast<ushort4*>(&xt[r * 64 + phys * 8 + (c4 & 1) * 4]) = b;
    }
    __syncthreads();

    const int w = t >> 6, lane = t & 63;
    const int rbase = w * 16;

    short8 A[2];
    #pragma unroll
    for (int kb = 0; kb < 2; ++kb) {
        int r = rbase + (lane & 15);
        int c16 = (kb * 4 + (lane >> 4)) ^ (r & 7);
        A[kb] = *reinterpret_cast<const short8*>(&xt[r * 64 + c16 * 8]);
    }

    f32x4 acc[4][4];
    #pragma unroll
    for (int m = 0; m < 4; ++m)
        #pragma unroll
        for (int nc = 0; nc < 4; ++nc)
            acc[m][nc] = (f32x4){0.f, 0.f, 0.f, 0.f};

    #pragma unroll
    for (int nc = 0; nc < 4; ++nc) {
        #pragma unroll
        for (int m = 0; m < 4; ++m) {
            #pragma unroll
            for (int kb = 0; kb < 2; ++kb) {
                short8 B = *reinterpret_cast<const short8*>(
                    &Wfrag[((((m * 4 + nc) * 2 + kb) * 64) + lane) * 8]);
                acc[m][nc] = __builtin_amdgcn_mfma_f32_16x16x32_bf16(A[kb], B, acc[m][nc], 0, 0, 0);
            }
        }
    }

    const int crow = rbase + ((lane >> 4) << 2);
    #pragma unroll
    for (int nc = 0; nc < 4; ++nc) {
        int c = nc * 16 + (lane & 15);
        float bkc = bk[c], bqc = bq[c], bvc = bv[c], bsc = bs[c] + bias[c];
        #pragma unroll
        for (int reg = 0; reg < 4; ++reg) {
            int grow = row0 + crow + reg;
            if (grow < nrows) {
                size_t o = (size_t)grow * D + c;
                EKh[o] = f2bf(__expf(-clamp60(acc[0][nc][reg] + bkc)));
                float eq = __expf(-clamp60(acc[1][nc][reg] + bqc));
                QV[o] = ((unsigned int)f2bf(acc[2][nc][reg] + bvc) << 16) | (unsigned int)f2bf(eq);
                AGG[o] = acc[3][nc][reg] + bsc;
            }
        }
    }
}

// ---------------- CSR build (node-level counters: chain depth ~12.5, low contention) ----------------
__global__ __launch_bounds__(256) void hist_rank(const int* __restrict__ dst,
                                                 int* __restrict__ counts,
                                                 int* __restrict__ rank, int nedges)
{
    int i = blockIdx.x * 256 + threadIdx.x;
    if (i < nedges) {
        int r = atomicAdd(&counts[dst[i]], 1);
        rank[i] = r;
    }
}

__global__ __launch_bounds__(256) void scan1(const int* __restrict__ counts,
                                             int* __restrict__ offs,
                                             int* __restrict__ bsums, int n)
{
    __shared__ int tmp[256];
    const int t = threadIdx.x;
    const int i = blockIdx.x * 256 + t;
    int v = (i < n) ? counts[i] : 0;
    tmp[t] = v;
    __syncthreads();
    for (int off = 1; off < 256; off <<= 1) {
        int add = (t >= off) ? tmp[t - off] : 0;
        __syncthreads();
        tmp[t] += add;
        __syncthreads();
    }
    if (i < n) offs[i] = tmp[t] - v;   // exclusive
    if (t == 255) bsums[blockIdx.x] = tmp[255];
}

__global__ __launch_bounds__(512) void scan2(int* __restrict__ bsums, int nb)
{
    __shared__ int tmp[512];
    const int t = threadIdx.x;
    int v = (t < nb) ? bsums[t] : 0;
    tmp[t] = v;
    __syncthreads();
    for (int off = 1; off < 512; off <<= 1) {
        int add = (t >= off) ? tmp[t - off] : 0;
        __syncthreads();
        tmp[t] += add;
        __syncthreads();
    }
    if (t < nb) bsums[t] = tmp[t] - v;
}

__global__ __launch_bounds__(256) void scan3(int* __restrict__ offs,
                                             const int* __restrict__ bsums,
                                             float* __restrict__ stats,
                                             int n, int nedges)
{
    int i = blockIdx.x * 256 + threadIdx.x;
    if (i < n) offs[i] += bsums[blockIdx.x];
    if (i == 0) offs[n] = nedges;
    if (i < 128) stats[i] = 0.f;          // zero BN accumulators for layer 1
}

// position = offs[dst] + rank  -> plain random store, no atomic dependency
__global__ __launch_bounds__(256) void scatter_norank(const int* __restrict__ src,
                                                      const int* __restrict__ dst,
                                                      const int* __restrict__ offs,
                                                      const int* __restrict__ rank,
                                                      int* __restrict__ csr_src, int nedges)
{
    int i = blockIdx.x * 256 + threadIdx.x;
    if (i < nedges) {
        int d = dst[i];
        csr_src[offs[d] + rank[i]] = src[i];
    }
}

// chunk -> first node map via binary search over offs
__global__ __launch_bounds__(256) void nstart_bs(const int* __restrict__ offs,
                                                 int* __restrict__ node_start,
                                                 int n, int NC)
{
    int c = blockIdx.x * 256 + threadIdx.x;
    if (c >= NC) return;
    int target = c * CH;
    int a = 0, bnd = n;
    while (a < bnd) {                 // first idx with offs[idx+1] > target
        int mid = (a + bnd) >> 1;
        if (offs[mid + 1] > target) bnd = mid; else a = mid + 1;
    }
    node_start[c] = a;
}

// ---------------- edge-parallel aggregation over CSR chunks ----------------
// NT: nontemporal (L2-bypass hint) QV gather — layer1/layer2 A/B.
template<bool NT>
__global__ __launch_bounds__(256) void edge_agg(
    const int* __restrict__ csr_src, const int* __restrict__ offs,
    const int* __restrict__ node_start,
    const unsigned short* __restrict__ EKh, const unsigned int* __restrict__ QV,
    float* __restrict__ AGG, int nnodes)
{
    const int lane  = threadIdx.x & 63;
    const int chunk = __builtin_amdgcn_readfirstlane((int)((blockIdx.x * 256 + threadIdx.x) >> 6));
    const int Etot  = offs[nnodes];
    const int e0 = chunk * CH;
    if (e0 >= Etot) return;
    const int e1 = min(e0 + CH, Etot);

    int n      = node_start[chunk];
    int nstart = offs[n];
    int nend   = offs[n + 1];

    float acc = 0.f;
    float ek  = bf2f(EKh[((size_t)n << 6) | lane]);

    auto flush = [&](bool partial) {
        int idx = (n << 6) | lane;
        if (partial) atomicAdd(&AGG[idx], acc);
        else         AGG[idx] += acc;
    };
    auto advance = [&](int eidx) {
        do { ++n; } while (offs[n + 1] == eidx);   // skip empty nodes
        nstart = eidx;
        nend   = offs[n + 1];
        acc = 0.f;
        ek  = bf2f(EKh[((size_t)n << 6) | lane]);
    };

    for (int e = e0; e < e1; e += 64) {
        const int cnt = min(64, e1 - e);
        int sAll = (lane < cnt) ? csr_src[e + lane] : 0;
        for (int b = 0; b < cnt; b += 16) {
            const int bc = min(16, cnt - b);
            unsigned int p[16];
            #pragma unroll
            for (int u = 0; u < 16; ++u) {
                if (u < bc) {
                    int s = __shfl(sAll, b + u);
                    if (NT) p[u] = __builtin_nontemporal_load(&QV[((size_t)s << 6) | lane]);
                    else    p[u] = QV[((size_t)s << 6) | lane];
                }
            }
            #pragma unroll
            for (int u = 0; u < 16; ++u) {
                if (u < bc) {
                    int eidx = e + b + u;
                    if (eidx == nend) { flush(nstart < e0); advance(eidx); }
                    float eq = __uint_as_float(p[u] << 16);
                    float vv = __uint_as_float(p[u] & 0xffff0000u);
                    float g  = __builtin_amdgcn_rcpf(fmaf(ek, eq, 1.0f));
                    acc = fmaf(g, vv, acc);
                }
            }
        }
    }
    flush((nstart < e0) || (nend > e1));
}

// ---------------- per-feature BN stats of relu(AGG) (no write-back) ----------------
__global__ __launch_bounds__(256) void relu_stats(
    const float* __restrict__ AGG, float* __restrict__ stats, int n4)
{
    __shared__ float ls[128];
    const int t = threadIdx.x;
    if (t < 128) ls[t] = 0.f;
    __syncthreads();
    int idx = blockIdx.x * 256 + t;
    const int stride = gridDim.x * 256;
    const int f0 = (idx << 2) & 63;
    float s0=0,s1=0,s2=0,s3=0,q0=0,q1=0,q2=0,q3=0;
    for (; idx < n4; idx += stride) {
        float4 a = reinterpret_cast<const float4*>(AGG)[idx];
        a.x = fmaxf(a.x, 0.f); a.y = fmaxf(a.y, 0.f);
        a.z = fmaxf(a.z, 0.f); a.w = fmaxf(a.w, 0.f);
        s0 += a.x; q0 = fmaf(a.x, a.x, q0);
        s1 += a.y; q1 = fmaf(a.y, a.y, q1);
        s2 += a.z; q2 = fmaf(a.z, a.z, q2);
        s3 += a.w; q3 = fmaf(a.w, a.w, q3);
    }
    atomicAdd(&ls[f0],     s0); atomicAdd(&ls[f0 + 1],     s1);
    atomicAdd(&ls[f0 + 2], s2); atomicAdd(&ls[f0 + 3],     s3);
    atomicAdd(&ls[64 + f0],     q0); atomicAdd(&ls[64 + f0 + 1], q1);
    atomicAdd(&ls[64 + f0 + 2], q2); atomicAdd(&ls[64 + f0 + 3], q3);
    __syncthreads();
    if (t < 128) atomicAdd(&stats[t], ls[t]);
}

// ---------------- finalize: scale/shift; re-zero sums for next layer ----------------
__global__ void finalize_stats(float* __restrict__ stats,
                               const float* __restrict__ gamma,
                               const float* __restrict__ beta, int nrows)
{
    int t = threadIdx.x;  // 64 threads
    float invN = 1.0f / (float)nrows;
    float mean = stats[t] * invN;
    float var  = stats[64 + t] * invN - mean * mean;
    float sc   = gamma[t] * rsqrtf(var + BN_EPS);
    stats[128 + t] = sc;
    stats[192 + t] = beta[t] - mean * sc;
    stats[t] = 0.f;
    stats[64 + t] = 0.f;
}

// ---------------- apply (final layer): out = relu(AGG)*scale + shift ----------------
__global__ __launch_bounds__(256) void apply_bn(
    const float* __restrict__ AGG, const float* __restrict__ stats,
    float* __restrict__ xout, int ntot4)
{
    int idx = blockIdx.x * 256 + threadIdx.x;
    const int stride = gridDim.x * 256;
    const float4* st4 = reinterpret_cast<const float4*>(stats);
    for (; idx < ntot4; idx += stride) {
        float4 a = reinterpret_cast<const float4*>(AGG)[idx];
        int c4 = idx & 15;
        float4 sc = st4[32 + c4];
        float4 sh = st4[48 + c4];
        float4 o;
        o.x = fmaxf(a.x, 0.f) * sc.x + sh.x;
        o.y = fmaxf(a.y, 0.f) * sc.y + sh.y;
        o.z = fmaxf(a.z, 0.f) * sc.z + sh.z;
        o.w = fmaxf(a.w, 0.f) * sc.w + sh.w;
        reinterpret_cast<float4*>(xout)[idx] = o;
    }
}

extern "C" void kernel_launch(void* const* d_in, const int* in_sizes, int n_in,
                              void* d_out, int out_size, void* d_ws, size_t ws_size,
                              hipStream_t stream)
{
    const float* x     = (const float*)d_in[0];
    const int*   ei    = (const int*)d_in[1];
    const float* Wk    = (const float*)d_in[3];
    const float* bk    = (const float*)d_in[4];
    const float* Wq    = (const float*)d_in[5];
    const float* bq    = (const float*)d_in[6];
    const float* Wv    = (const float*)d_in[7];
    const float* bv    = (const float*)d_in[8];
    const float* Ws    = (const float*)d_in[9];
    const float* bs    = (const float*)d_in[10];
    const float* bias  = (const float*)d_in[11];
    const float* gamma = (const float*)d_in[12];
    const float* beta  = (const float*)d_in[13];

    const int nrows  = in_sizes[0] / D;     // 100000
    const int nedges = in_sizes[1] / 2;     // 1250000
    const int nm     = nrows * D;
    const int NC     = (nedges + CH - 1) / CH;            // chunks

    float* out = (float*)d_out;
    float* ws  = (float*)d_ws;
    unsigned short* EKh = (unsigned short*)ws;            // nm u16
    unsigned int* QV = (unsigned int*)(EKh + nm);         // nm u32
    float* AGG = (float*)(QV + nm);                       // nm f32
    float* stats = AGG + nm;                              // 256 f32
    int* counts  = (int*)(stats + 256);                   // nrows
    int* offs    = counts + nrows;                        // nrows+1
    int* bsums   = offs + nrows + 1;                      // 512
    int* nstart_map = bsums + 512;                        // NC
    int* csr_src = nstart_map + NC;                       // nedges
    int* rank    = csr_src + nedges;                      // nedges
    unsigned short* Wfrag = (unsigned short*)(rank + nedges);  // 32768 u16

    const int* srcI = ei;
    const int* dstI = ei + nedges;

    const int gemm_blocks = (nrows + 63) / 64;
    const int edge_blocks = (nedges + 255) / 256;
    const int node_blocks = (nrows + 255) / 256;          // 391 (<512 for scan2)
    const int agg_blocks  = (NC + 3) / 4;                 // 1 wave per chunk

    // ---- weight prep + node-level CSR build ----
    prep_weights<<<128, 256, 0, stream>>>(Wk, Wq, Wv, Ws, Wfrag);
    hipMemsetAsync(counts, 0, (size_t)nrows * sizeof(int), stream);
    hist_rank<<<edge_blocks, 256, 0, stream>>>(dstI, counts, rank, nedges);
    scan1<<<node_blocks, 256, 0, stream>>>(counts, offs, bsums, nrows);
    scan2<<<1, 512, 0, stream>>>(bsums, node_blocks);
    scan3<<<node_blocks, 256, 0, stream>>>(offs, bsums, stats, nrows, nedges);
    scatter_norank<<<edge_blocks, 256, 0, stream>>>(srcI, dstI, offs, rank, csr_src, nedges);
    nstart_bs<<<(NC + 255) / 256, 256, 0, stream>>>(offs, nstart_map, nrows, NC);

    // ---- layer 1 (A: nontemporal QV gather) ----
    gemm_fused<false><<<gemm_blocks, 256, 0, stream>>>(x, Wfrag,
        bk, bq, bv, bs, bias, stats, EKh, QV, AGG, nrows);
    edge_agg<true><<<agg_blocks, 256, 0, stream>>>(csr_src, offs, nstart_map, EKh, QV, AGG, nrows);
    relu_stats<<<1024, 256, 0, stream>>>(AGG, stats, nm / 4);
    finalize_stats<<<1, 64, 0, stream>>>(stats, gamma, beta, nrows);

    // ---- layer 2 (B: cached QV gather; relu+BN of layer 1 fused into MFMA staging) ----
    gemm_fused<true><<<gemm_blocks, 256, 0, stream>>>(AGG, Wfrag + 16384,
        bk + D, bq + D, bv + D, bs + D, bias + D, stats, EKh, QV, AGG, nrows);
    edge_agg<false><<<agg_blocks, 256, 0, stream>>>(csr_src, offs, nstart_map, EKh, QV, AGG, nrows);
    relu_stats<<<1024, 256, 0, stream>>>(AGG, stats, nm / 4);
    finalize_stats<<<1, 64, 0, stream>>>(stats, gamma + D, beta + D, nrows);
    apply_bn<<<2048, 256, 0, stream>>>(AGG, stats, out, nm / 4);
}

// Round 9
// 339.744 us; speedup vs baseline: 1.3070x; 1.2322x over previous
//
#include <hip/hip_runtime.h>
#include <math.h>

#define D 64
#define BN_EPS 1e-5f
#define CH 160          // edges per chunk (edge_agg work unit)
#define BSH 7           // bucket = 128 consecutive dst nodes
#define BCAP 8192       // per-bucket LDS capacity in bucket_csr (mean ~1600)
#define NBLK 256        // fat blocks for matrix binning (must equal blockDim)

using short8 = __attribute__((ext_vector_type(8))) short;
using f32x4  = __attribute__((ext_vector_type(4))) float;

static __device__ __forceinline__ unsigned short f2bf(float f) {
    unsigned int u = __float_as_uint(f);
    unsigned int r = (u + 0x7fffu + ((u >> 16) & 1u)) >> 16;
    return (unsigned short)r;
}
static __device__ __forceinline__ float bf2f(unsigned short u) {
    return __uint_as_float(((unsigned int)u) << 16);
}
static __device__ __forceinline__ float clamp60(float x) {
    return fminf(fmaxf(x, -60.f), 60.f);
}

// ---------------- weight prep: fragment-linear bf16 for mfma_f32_16x16x32_bf16 ----------------
__global__ __launch_bounds__(256) void prep_weights(
    const float* __restrict__ Wk, const float* __restrict__ Wq,
    const float* __restrict__ Wv, const float* __restrict__ Ws,
    unsigned short* __restrict__ Wfrag)
{
    int idx = blockIdx.x * 256 + threadIdx.x;      // 32768 total
    int i    = idx & 7;
    int lane = (idx >> 3) & 63;
    int kb   = (idx >> 9) & 1;
    int nc   = (idx >> 10) & 3;
    int m    = (idx >> 12) & 3;
    int l    = (idx >> 14) & 1;
    int k = kb * 32 + (lane >> 4) * 8 + i;
    int n = nc * 16 + (lane & 15);
    const float* W = (m == 0) ? Wk : (m == 1) ? Wq : (m == 2) ? Wv : Ws;
    Wfrag[idx] = f2bf(W[(size_t)l * 4096 + k * 64 + n]);
}

// ---------------- fused 4-GEMM via MFMA ----------------
template<bool APPLY_BN>
__global__ __launch_bounds__(256) void gemm_fused(
    const float* x,                       // may alias AGG (own rows only)
    const unsigned short* __restrict__ Wfrag,
    const float* __restrict__ bk, const float* __restrict__ bq,
    const float* __restrict__ bv, const float* __restrict__ bs,
    const float* __restrict__ bias, const float* __restrict__ stats,
    unsigned short* __restrict__ EKh, unsigned int* __restrict__ QV,
    float* AGG, int nrows)
{
    __shared__ unsigned short xt[64 * 64];   // bf16 tile, XOR-swizzled 16B chunks
    const int t = threadIdx.x;
    const int row0 = blockIdx.x * 64;

    #pragma unroll
    for (int it = 0; it < 4; ++it) {
        int fidx = t + it * 256;
        int r = fidx >> 4, c4 = fidx & 15;
        int grow = row0 + r;
        float4 v = make_float4(0.f, 0.f, 0.f, 0.f);
        if (grow < nrows)
            v = *reinterpret_cast<const float4*>(&x[(size_t)grow * D + c4 * 4]);
        if (APPLY_BN) {
            const float4* st4 = reinterpret_cast<const float4*>(stats);
            float4 sc = st4[32 + c4], sh = st4[48 + c4];
            v.x = fmaxf(v.x, 0.f) * sc.x + sh.x;
            v.y = fmaxf(v.y, 0.f) * sc.y + sh.y;
            v.z = fmaxf(v.z, 0.f) * sc.z + sh.z;
            v.w = fmaxf(v.w, 0.f) * sc.w + sh.w;
        }
        ushort4 b;
        b.x = f2bf(v.x); b.y = f2bf(v.y); b.z = f2bf(v.z); b.w = f2bf(v.w);
        int phys = (c4 >> 1) ^ (r & 7);      // 16B-chunk XOR swizzle
        *reinterpret_cast<ushort4*>(&xt[r * 64 + phys * 8 + (c4 & 1) * 4]) = b;
    }
    __syncthreads();

    const int w = t >> 6, lane = t & 63;
    const int rbase = w * 16;

    short8 A[2];
    #pragma unroll
    for (int kb = 0; kb < 2; ++kb) {
        int r = rbase + (lane & 15);
        int c16 = (kb * 4 + (lane >> 4)) ^ (r & 7);
        A[kb] = *reinterpret_cast<const short8*>(&xt[r * 64 + c16 * 8]);
    }

    f32x4 acc[4][4];
    #pragma unroll
    for (int m = 0; m < 4; ++m)
        #pragma unroll
        for (int nc = 0; nc < 4; ++nc)
            acc[m][nc] = (f32x4){0.f, 0.f, 0.f, 0.f};

    #pragma unroll
    for (int nc = 0; nc < 4; ++nc) {
        #pragma unroll
        for (int m = 0; m < 4; ++m) {
            #pragma unroll
            for (int kb = 0; kb < 2; ++kb) {
                short8 B = *reinterpret_cast<const short8*>(
                    &Wfrag[((((m * 4 + nc) * 2 + kb) * 64) + lane) * 8]);
                acc[m][nc] = __builtin_amdgcn_mfma_f32_16x16x32_bf16(A[kb], B, acc[m][nc], 0, 0, 0);
            }
        }
    }

    const int crow = rbase + ((lane >> 4) << 2);
    #pragma unroll
    for (int nc = 0; nc < 4; ++nc) {
        int c = nc * 16 + (lane & 15);
        float bkc = bk[c], bqc = bq[c], bvc = bv[c], bsc = bs[c] + bias[c];
        #pragma unroll
        for (int reg = 0; reg < 4; ++reg) {
            int grow = row0 + crow + reg;
            if (grow < nrows) {
                size_t o = (size_t)grow * D + c;
                EKh[o] = f2bf(__expf(-clamp60(acc[0][nc][reg] + bkc)));
                float eq = __expf(-clamp60(acc[1][nc][reg] + bqc));
                QV[o] = ((unsigned int)f2bf(acc[2][nc][reg] + bvc) << 16) | (unsigned int)f2bf(eq);
                AGG[o] = acc[3][nc][reg] + bsc;
            }
        }
    }
}

// ---------------- matrix-binned CSR build (zero global atomics) ----------------
// pass 1: per-fat-block LDS histogram -> cnt[block][NB]  (coalesced row store)
__global__ __launch_bounds__(256) void bin_count(const int* __restrict__ dst,
                                                 int* __restrict__ cnt,
                                                 int nedges, int NB)
{
    __shared__ int h[1024];
    const int t = threadIdx.x, b = blockIdx.x;
    for (int i = t; i < NB; i += 256) h[i] = 0;
    __syncthreads();
    const int e0 = (int)(((long long)nedges * b) / NBLK);
    const int e1 = (int)(((long long)nedges * (b + 1)) / NBLK);
    for (int i = e0 + t; i < e1; i += 256)
        atomicAdd(&h[dst[i] >> BSH], 1);
    __syncthreads();
    for (int i = t; i < NB; i += 256) cnt[b * NB + i] = h[i];
}

// per-bucket scan over the 256 block rows: basel[block][bucket], btot[bucket]
__global__ __launch_bounds__(256) void scan_mat(const int* __restrict__ cnt,
                                                int* __restrict__ basel,
                                                int* __restrict__ btot, int NB)
{
    __shared__ int tmp[256];
    const int k = blockIdx.x;    // bucket
    const int t = threadIdx.x;   // block index
    int v = cnt[t * NB + k];
    tmp[t] = v;
    __syncthreads();
    for (int off = 1; off < 256; off <<= 1) {
        int add = (t >= off) ? tmp[t - off] : 0;
        __syncthreads();
        tmp[t] += add;
        __syncthreads();
    }
    basel[t * NB + k] = tmp[t] - v;      // exclusive over blocks, within bucket
    if (t == 255) btot[k] = tmp[255];
}

// scan bucket totals (1 block); also zero BN stats and set offs[n]
__global__ __launch_bounds__(1024) void scan_buckets(const int* __restrict__ btot,
                                                     int* __restrict__ boff,
                                                     float* __restrict__ stats,
                                                     int* __restrict__ offs,
                                                     int NB, int n, int nedges)
{
    __shared__ int tmp[1024];
    const int t = threadIdx.x;
    int v = (t < NB) ? btot[t] : 0;
    tmp[t] = v;
    __syncthreads();
    for (int off = 1; off < 1024; off <<= 1) {
        int add = (t >= off) ? tmp[t - off] : 0;
        __syncthreads();
        tmp[t] += add;
        __syncthreads();
    }
    if (t < NB) boff[t] = tmp[t] - v;
    if (t < 128) stats[t] = 0.f;
    if (t == 0) offs[n] = nedges;
}

// pass 2: emit (src<<BSH | dst&127) to exact position via LDS cursors (no global atomics)
__global__ __launch_bounds__(256) void bin_emit(const int* __restrict__ src,
                                                const int* __restrict__ dst,
                                                const int* __restrict__ basel,
                                                const int* __restrict__ boff,
                                                unsigned int* __restrict__ bin,
                                                int nedges, int NB)
{
    __shared__ int cur[1024];
    const int t = threadIdx.x, b = blockIdx.x;
    for (int i = t; i < NB; i += 256) cur[i] = boff[i] + basel[b * NB + i];
    __syncthreads();
    const int e0 = (int)(((long long)nedges * b) / NBLK);
    const int e1 = (int)(((long long)nedges * (b + 1)) / NBLK);
    for (int i = e0 + t; i < e1; i += 256) {
        int d = dst[i];
        int pos = atomicAdd(&cur[d >> BSH], 1);
        bin[pos] = ((unsigned int)src[i] << BSH) | (unsigned int)(d & ((1 << BSH) - 1));
    }
}

// one block per bucket: exact CSR within bucket, all in LDS, coalesced global IO
__global__ __launch_bounds__(256) void bucket_csr(const unsigned int* __restrict__ bin,
                                                  const int* __restrict__ boff,
                                                  const int* __restrict__ btot,
                                                  int* __restrict__ offs,
                                                  int* __restrict__ csr_src, int n)
{
    __shared__ unsigned int lsrc[BCAP];
    __shared__ int ldeg[128], loff[128], lcur[128];
    const int t = threadIdx.x;
    const int b = blockIdx.x;
    const int base = boff[b];
    const int cnt  = btot[b];

    if (t < 128) ldeg[t] = 0;
    __syncthreads();
    for (int j = t; j < cnt; j += 256)
        atomicAdd(&ldeg[bin[base + j] & ((1 << BSH) - 1)], 1);
    __syncthreads();
    if (t < 128) loff[t] = ldeg[t];
    __syncthreads();
    for (int off = 1; off < 128; off <<= 1) {
        int add = (t < 128 && t >= off) ? loff[t - off] : 0;
        __syncthreads();
        if (t < 128) loff[t] += add;
        __syncthreads();
    }
    if (t < 128) {
        int ex = loff[t] - ldeg[t];
        lcur[t] = ex;
        int node = (b << BSH) + t;
        if (node < n) offs[node] = base + ex;
    }
    __syncthreads();
    for (int j = t; j < cnt; j += 256) {
        unsigned int e = bin[base + j];
        int pos = atomicAdd(&lcur[e & ((1 << BSH) - 1)], 1);
        lsrc[pos] = e >> BSH;
    }
    __syncthreads();
    for (int j = t; j < cnt; j += 256)
        csr_src[base + j] = (int)lsrc[j];
}

// chunk -> first node map via binary search over offs
__global__ __launch_bounds__(256) void nstart_bs(const int* __restrict__ offs,
                                                 int* __restrict__ node_start,
                                                 int n, int NC)
{
    int c = blockIdx.x * 256 + threadIdx.x;
    if (c >= NC) return;
    int target = c * CH;
    int a = 0, bnd = n;
    while (a < bnd) {                 // first idx with offs[idx+1] > target
        int mid = (a + bnd) >> 1;
        if (offs[mid + 1] > target) bnd = mid; else a = mid + 1;
    }
    node_start[c] = a;
}

// ---------------- edge-parallel aggregation over CSR chunks (plain cached loads) ----------------
__global__ __launch_bounds__(256) void edge_agg(
    const int* __restrict__ csr_src, const int* __restrict__ offs,
    const int* __restrict__ node_start,
    const unsigned short* __restrict__ EKh, const unsigned int* __restrict__ QV,
    float* __restrict__ AGG, int nnodes)
{
    const int lane  = threadIdx.x & 63;
    const int chunk = __builtin_amdgcn_readfirstlane((int)((blockIdx.x * 256 + threadIdx.x) >> 6));
    const int Etot  = offs[nnodes];
    const int e0 = chunk * CH;
    if (e0 >= Etot) return;
    const int e1 = min(e0 + CH, Etot);

    int n      = node_start[chunk];
    int nstart = offs[n];
    int nend   = offs[n + 1];

    float acc = 0.f;
    float ek  = bf2f(EKh[((size_t)n << 6) | lane]);

    auto flush = [&](bool partial) {
        int idx = (n << 6) | lane;
        if (partial) atomicAdd(&AGG[idx], acc);
        else         AGG[idx] += acc;
    };
    auto advance = [&](int eidx) {
        do { ++n; } while (offs[n + 1] == eidx);   // skip empty nodes
        nstart = eidx;
        nend   = offs[n + 1];
        acc = 0.f;
        ek  = bf2f(EKh[((size_t)n << 6) | lane]);
    };

    for (int e = e0; e < e1; e += 64) {
        const int cnt = min(64, e1 - e);
        int sAll = (lane < cnt) ? csr_src[e + lane] : 0;
        for (int b = 0; b < cnt; b += 16) {
            const int bc = min(16, cnt - b);
            unsigned int p[16];
            #pragma unroll
            for (int u = 0; u < 16; ++u) {
                if (u < bc) {
                    int s = __shfl(sAll, b + u);
                    p[u] = QV[((size_t)s << 6) | lane];
                }
            }
            #pragma unroll
            for (int u = 0; u < 16; ++u) {
                if (u < bc) {
                    int eidx = e + b + u;
                    if (eidx == nend) { flush(nstart < e0); advance(eidx); }
                    float eq = __uint_as_float(p[u] << 16);
                    float vv = __uint_as_float(p[u] & 0xffff0000u);
                    float g  = __builtin_amdgcn_rcpf(fmaf(ek, eq, 1.0f));
                    acc = fmaf(g, vv, acc);
                }
            }
        }
    }
    flush((nstart < e0) || (nend > e1));
}

// ---------------- per-feature BN stats of relu(AGG) (no write-back) ----------------
__global__ __launch_bounds__(256) void relu_stats(
    const float* __restrict__ AGG, float* __restrict__ stats, int n4)
{
    __shared__ float ls[128];
    const int t = threadIdx.x;
    if (t < 128) ls[t] = 0.f;
    __syncthreads();
    int idx = blockIdx.x * 256 + t;
    const int stride = gridDim.x * 256;
    const int f0 = (idx << 2) & 63;
    float s0=0,s1=0,s2=0,s3=0,q0=0,q1=0,q2=0,q3=0;
    for (; idx < n4; idx += stride) {
        float4 a = reinterpret_cast<const float4*>(AGG)[idx];
        a.x = fmaxf(a.x, 0.f); a.y = fmaxf(a.y, 0.f);
        a.z = fmaxf(a.z, 0.f); a.w = fmaxf(a.w, 0.f);
        s0 += a.x; q0 = fmaf(a.x, a.x, q0);
        s1 += a.y; q1 = fmaf(a.y, a.y, q1);
        s2 += a.z; q2 = fmaf(a.z, a.z, q2);
        s3 += a.w; q3 = fmaf(a.w, a.w, q3);
    }
    atomicAdd(&ls[f0],     s0); atomicAdd(&ls[f0 + 1],     s1);
    atomicAdd(&ls[f0 + 2], s2); atomicAdd(&ls[f0 + 3],     s3);
    atomicAdd(&ls[64 + f0],     q0); atomicAdd(&ls[64 + f0 + 1], q1);
    atomicAdd(&ls[64 + f0 + 2], q2); atomicAdd(&ls[64 + f0 + 3], q3);
    __syncthreads();
    if (t < 128) atomicAdd(&stats[t], ls[t]);
}

// ---------------- finalize: scale/shift; re-zero sums for next layer ----------------
__global__ void finalize_stats(float* __restrict__ stats,
                               const float* __restrict__ gamma,
                               const float* __restrict__ beta, int nrows)
{
    int t = threadIdx.x;  // 64 threads
    float invN = 1.0f / (float)nrows;
    float mean = stats[t] * invN;
    float var  = stats[64 + t] * invN - mean * mean;
    float sc   = gamma[t] * rsqrtf(var + BN_EPS);
    stats[128 + t] = sc;
    stats[192 + t] = beta[t] - mean * sc;
    stats[t] = 0.f;
    stats[64 + t] = 0.f;
}

// ---------------- apply (final layer): out = relu(AGG)*scale + shift ----------------
__global__ __launch_bounds__(256) void apply_bn(
    const float* __restrict__ AGG, const float* __restrict__ stats,
    float* __restrict__ xout, int ntot4)
{
    int idx = blockIdx.x * 256 + threadIdx.x;
    const int stride = gridDim.x * 256;
    const float4* st4 = reinterpret_cast<const float4*>(stats);
    for (; idx < ntot4; idx += stride) {
        float4 a = reinterpret_cast<const float4*>(AGG)[idx];
        int c4 = idx & 15;
        float4 sc = st4[32 + c4];
        float4 sh = st4[48 + c4];
        float4 o;
        o.x = fmaxf(a.x, 0.f) * sc.x + sh.x;
        o.y = fmaxf(a.y, 0.f) * sc.y + sh.y;
        o.z = fmaxf(a.z, 0.f) * sc.z + sh.z;
        o.w = fmaxf(a.w, 0.f) * sc.w + sh.w;
        reinterpret_cast<float4*>(xout)[idx] = o;
    }
}

extern "C" void kernel_launch(void* const* d_in, const int* in_sizes, int n_in,
                              void* d_out, int out_size, void* d_ws, size_t ws_size,
                              hipStream_t stream)
{
    const float* x     = (const float*)d_in[0];
    const int*   ei    = (const int*)d_in[1];
    const float* Wk    = (const float*)d_in[3];
    const float* bk    = (const float*)d_in[4];
    const float* Wq    = (const float*)d_in[5];
    const float* bq    = (const float*)d_in[6];
    const float* Wv    = (const float*)d_in[7];
    const float* bv    = (const float*)d_in[8];
    const float* Ws    = (const float*)d_in[9];
    const float* bs    = (const float*)d_in[10];
    const float* bias  = (const float*)d_in[11];
    const float* gamma = (const float*)d_in[12];
    const float* beta  = (const float*)d_in[13];

    const int nrows  = in_sizes[0] / D;     // 100000
    const int nedges = in_sizes[1] / 2;     // 1250000
    const int nm     = nrows * D;
    const int NB     = (nrows + (1 << BSH) - 1) >> BSH;   // 782 buckets
    const int NC     = (nedges + CH - 1) / CH;            // chunks

    float* out = (float*)d_out;
    float* ws  = (float*)d_ws;
    unsigned short* EKh = (unsigned short*)ws;            // nm u16
    unsigned int* QV = (unsigned int*)(EKh + nm);         // nm u32
    float* AGG = (float*)(QV + nm);                       // nm f32
    float* stats = AGG + nm;                              // 256 f32
    int* offs    = (int*)(stats + 256);                   // nrows+1
    unsigned int* bin = (unsigned int*)(offs + nrows + 1);// nedges
    int* csr_src = (int*)(bin + nedges);                  // nedges
    int* cnt     = csr_src + nedges;                      // NBLK*NB
    int* basel   = cnt + NBLK * NB;                       // NBLK*NB
    int* btot    = basel + NBLK * NB;                     // NB
    int* boff    = btot + NB;                             // NB
    int* nstart_map = boff + NB;                          // NC
    unsigned short* Wfrag = (unsigned short*)(nstart_map + NC);  // 32768 u16

    const int* srcI = ei;
    const int* dstI = ei + nedges;

    const int gemm_blocks = (nrows + 63) / 64;
    const int agg_blocks  = (NC + 3) / 4;                 // 1 wave per chunk

    // ---- weight prep + matrix-binned CSR build ----
    prep_weights<<<128, 256, 0, stream>>>(Wk, Wq, Wv, Ws, Wfrag);
    bin_count<<<NBLK, 256, 0, stream>>>(dstI, cnt, nedges, NB);
    scan_mat<<<NB, 256, 0, stream>>>(cnt, basel, btot, NB);
    scan_buckets<<<1, 1024, 0, stream>>>(btot, boff, stats, offs, NB, nrows, nedges);
    bin_emit<<<NBLK, 256, 0, stream>>>(srcI, dstI, basel, boff, bin, nedges, NB);
    bucket_csr<<<NB, 256, 0, stream>>>(bin, boff, btot, offs, csr_src, nrows);
    nstart_bs<<<(NC + 255) / 256, 256, 0, stream>>>(offs, nstart_map, nrows, NC);

    // ---- layer 1 ----
    gemm_fused<false><<<gemm_blocks, 256, 0, stream>>>(x, Wfrag,
        bk, bq, bv, bs, bias, stats, EKh, QV, AGG, nrows);
    edge_agg<<<agg_blocks, 256, 0, stream>>>(csr_src, offs, nstart_map, EKh, QV, AGG, nrows);
    relu_stats<<<1024, 256, 0, stream>>>(AGG, stats, nm / 4);
    finalize_stats<<<1, 64, 0, stream>>>(stats, gamma, beta, nrows);

    // ---- layer 2 (relu+BN of layer 1 fused into MFMA staging) ----
    gemm_fused<true><<<gemm_blocks, 256, 0, stream>>>(AGG, Wfrag + 16384,
        bk + D, bq + D, bv + D, bs + D, bias + D, stats, EKh, QV, AGG, nrows);
    edge_agg<<<agg_blocks, 256, 0, stream>>>(csr_src, offs, nstart_map, EKh, QV, AGG, nrows);
    relu_stats<<<1024, 256, 0, stream>>>(AGG, stats, nm / 4);
    finalize_stats<<<1, 64, 0, stream>>>(stats, gamma + D, beta + D, nrows);
    apply_bn<<<2048, 256, 0, stream>>>(AGG, stats, out, nm / 4);
}